// Round 9
// baseline (245.174 us; speedup 1.0000x reference)
//
#include <hip/hip_runtime.h>

#define BSZ 64
#define SEQ 512
#define HID 768
#define NK  21
#define NSEG 64        // segments per batch
#define SEGLEN 8       // time-steps per segment (NSEG*SEGLEN == SEQ)

typedef short bf16x8 __attribute__((ext_vector_type(8)));
typedef float f32x4  __attribute__((ext_vector_type(4)));

__device__ __forceinline__ unsigned f2bf1(float x) {   // RNE fp32->bf16
    unsigned u = __float_as_uint(x);
    return (u + 0x7fffu + ((u >> 16) & 1u)) >> 16;
}
__device__ __forceinline__ unsigned f2bf_pk(float lo, float hi) {
    return f2bf1(lo) | (f2bf1(hi) << 16);
}

// ---------------- W pre-convert: WT[32][768] bf16, transposed, zero-padded ---
__global__ __launch_bounds__(256) void wconv_kernel(
    const float* __restrict__ W, unsigned short* __restrict__ WT)
{
    const int idx = blockIdx.x * 256 + threadIdx.x;    // 0 .. 24575
    const int n = idx / HID;
    const int k = idx - n * HID;
    unsigned short v = 0;
    if (n < NK) v = (unsigned short)f2bf1(W[(size_t)k * NK + n]);
    WT[idx] = v;
}

// ---------------- GEMM + bias (bf16 MFMA) — UNCHANGED from R8 ----------------
__global__ __launch_bounds__(256) void gemm_bias_kernel(
    const float* __restrict__ hidden, const unsigned short* __restrict__ WT,
    const float* __restrict__ bias, float* __restrict__ out)
{
    const int tid  = threadIdx.x;
    const int lane = tid & 63;
    const int wv   = tid >> 6;
    const int n    = lane & 15;
    const int quad = lane >> 4;

    const int arow = blockIdx.x * 64 + wv * 16 + n;
    const float* ap = hidden + (size_t)arow * HID + quad * 8;
    const bf16x8* bp0 = (const bf16x8*)(WT + (size_t)n * HID + quad * 8);
    const bf16x8* bp1 = (const bf16x8*)(WT + (size_t)(16 + n) * HID + quad * 8);

    f32x4 acc0 = {0.f, 0.f, 0.f, 0.f};
    f32x4 acc1 = {0.f, 0.f, 0.f, 0.f};

    float4 c0a = *(const float4*)(ap + 0);
    float4 c0b = *(const float4*)(ap + 4);

    #pragma unroll
    for (int c = 0; c < HID / 32; ++c) {
        float4 c1a, c1b;
        if (c + 1 < HID / 32) {
            c1a = *(const float4*)(ap + (c + 1) * 32);
            c1b = *(const float4*)(ap + (c + 1) * 32 + 4);
        }
        union { bf16x8 v; unsigned u[4]; } af;
        af.u[0] = f2bf_pk(c0a.x, c0a.y);
        af.u[1] = f2bf_pk(c0a.z, c0a.w);
        af.u[2] = f2bf_pk(c0b.x, c0b.y);
        af.u[3] = f2bf_pk(c0b.z, c0b.w);

        const bf16x8 b0 = bp0[c * 4];
        const bf16x8 b1 = bp1[c * 4];

        acc0 = __builtin_amdgcn_mfma_f32_16x16x32_bf16(af.v, b0, acc0, 0, 0, 0);
        acc1 = __builtin_amdgcn_mfma_f32_16x16x32_bf16(af.v, b1, acc1, 0, 0, 0);
        c0a = c1a; c0b = c1b;
    }

    const float b0v = bias[n];
    const float b1v = (n < NK - 16) ? bias[16 + n] : 0.f;
    const int rbase = blockIdx.x * 64 + wv * 16 + quad * 4;
    #pragma unroll
    for (int r = 0; r < 4; ++r) {
        float* op = out + (size_t)(rbase + r) * NK;
        op[n] = acc0[r] + b0v;
        if (n < NK - 16) op[16 + n] = acc1[r] + b1v;
    }
}

// ---------------- CRF pre-pass: per-segment matrix products --------------------
// One wave per (batch b, segment s). N_s = Prod_{t=8s+1..8s+8} M_t,
// M_t[i][j] = exp(trans[i][j]) * exp(lg[t][j]-C[t]) for t<L, identity for t>=L.
// Lane = (i = row, g = 7-col group); E columns held in 147 registers; row
// gather via 21 ds_bpermute; renorm by entry[0][0] each multiply (log kept).
__global__ __launch_bounds__(64) void prepass_kernel(
    const float* __restrict__ logits, const float* __restrict__ trans,
    const int* __restrict__ mask,
    float* __restrict__ Nrow, float* __restrict__ Ncol,
    float* __restrict__ rlog)
{
    const int bs   = blockIdx.x;                 // b*NSEG + s
    const int b    = bs >> 6;
    const int s    = bs & 63;
    const int lane = threadIdx.x;
    int g = lane / 21; if (g > 2) g = 2;         // lane 63 duplicates (20,2)
    int i = lane - g * 21; if (i > 20) i = 20;
    const int j0 = 7 * g;

    // sequence length
    const int* msk = mask + b * SEQ;
    int cnt = 0;
    #pragma unroll
    for (int t = 0; t < SEQ / 64; ++t) cnt += (msk[lane + 64 * t] != 0);
    #pragma unroll
    for (int off = 32; off > 0; off >>= 1) cnt += __shfl_xor(cnt, off, 64);
    const int L = cnt;

    // E[k][j] for this lane's 7 columns
    float E[21][7];
    #pragma unroll
    for (int k = 0; k < 21; ++k)
        #pragma unroll
        for (int jl = 0; jl < 7; ++jl)
            E[k][jl] = __expf(trans[k * NK + j0 + jl]);

    const float* lg = logits + (size_t)b * SEQ * NK;

    float P[7];
    float rl = 0.f;
    const int t0 = s * SEGLEN + 1;

    if (t0 < L) {                                // P := M_{t0}
        const float C = lg[t0 * NK];
        #pragma unroll
        for (int jl = 0; jl < 7; ++jl)
            P[jl] = E[i][jl] * __expf(lg[t0 * NK + j0 + jl] - C);
    } else {                                     // identity
        #pragma unroll
        for (int jl = 0; jl < 7; ++jl) P[jl] = (i == j0 + jl) ? 1.f : 0.f;
    }

#define BPF(v, idx) __uint_as_float(__builtin_amdgcn_ds_bpermute((idx) * 4, __float_as_uint(v)))

    #pragma unroll
    for (int u = 1; u < SEGLEN; ++u) {
        const int t = t0 + u;
        if (t < L) {                             // wave-uniform branch
            float row[21];                       // full row i of P
            #pragma unroll
            for (int k = 0; k < 21; ++k)
                row[k] = BPF(P[k % 7], (k / 7) * 21 + i);

            const float C = lg[t * NK];
            float X[7];
            #pragma unroll
            for (int jl = 0; jl < 7; ++jl)
                X[jl] = __expf(lg[t * NK + j0 + jl] - C);

            #pragma unroll
            for (int jl = 0; jl < 7; ++jl) {
                float s0 = row[0] * E[0][jl];
                float s1 = row[1] * E[1][jl];
                float s2 = row[2] * E[2][jl];
                #pragma unroll
                for (int k = 3; k < 21; k += 3) {
                    s0 = fmaf(row[k    ], E[k    ][jl], s0);
                    s1 = fmaf(row[k + 1], E[k + 1][jl], s1);
                    s2 = fmaf(row[k + 2], E[k + 2][jl], s2);
                }
                P[jl] = ((s0 + s1) + s2) * X[jl];
            }
            // renorm by P[0][0] (lane 0, reg 0); exact algebra: log(m) kept
            const float m = BPF(P[0], 0);
            const float r = __builtin_amdgcn_rcpf(m);
            #pragma unroll
            for (int jl = 0; jl < 7; ++jl) P[jl] *= r;
            rl += __logf(m);
        }
    }
#undef BPF

    if (lane < 63) {                             // lane 63 is a duplicate
        float* nr = Nrow + (size_t)bs * 441 + i * 21 + j0;
        #pragma unroll
        for (int jl = 0; jl < 7; ++jl) nr[jl] = P[jl];
        float* nc = Ncol + (size_t)bs * 441 + i;
        #pragma unroll
        for (int jl = 0; jl < 7; ++jl) nc[(j0 + jl) * 21] = P[jl];
    }
    if (lane == 0) rlog[bs] = rl;
}

// ---------------- CRF scan: 32 matrix-vector steps per wave -------------------
__global__ __launch_bounds__(128) void scan_kernel(
    const float* __restrict__ logits,
    const float* __restrict__ start_t,
    const float* __restrict__ trans,
    const float* __restrict__ end_t,
    const int* __restrict__ labels,
    const int* __restrict__ mask,
    const float* __restrict__ Nrow, const float* __restrict__ Ncol,
    const float* __restrict__ rlog,
    float* __restrict__ per_batch)
{
    __shared__ float comb[26];                   // [0..20] beta_m, [21] OB, [22/23] num

    const int b    = blockIdx.x;
    const int tid  = threadIdx.x;
    const int lane = tid & 63;
    const int wid  = tid >> 6;                   // 0 = forward, 1 = backward

    const float* lg = logits + (size_t)b * SEQ * NK;
    const int* lab = labels + b * SEQ;
    const int* msk = mask   + b * SEQ;

    int cnt = 0;
    #pragma unroll
    for (int t = 0; t < SEQ / 64; ++t) cnt += (msk[lane + 64 * t] != 0);
    #pragma unroll
    for (int off = 32; off > 0; off >>= 1) cnt += __shfl_xor(cnt, off, 64);
    const int L = cnt;

    {   // numerator partials over 128 threads (global reads, L2-hot)
        float numacc = 0.f;
        for (int t = tid; t < L; t += 128) {
            if (t == 0) numacc += start_t[lab[0]] + lg[lab[0]];
            else        numacc += lg[t * NK + lab[t]] + trans[lab[t - 1] * NK + lab[t]];
        }
        if (tid == 0) numacc += end_t[lab[L - 1]];
        #pragma unroll
        for (int off = 32; off > 0; off >>= 1) numacc += __shfl_xor(numacc, off, 64);
        if (lane == 0) comb[22 + wid] = numacc;
    }

    // rlog partial sum: fwd wave sums s=0..31, bwd s=32..63
    float rls = (lane < 32) ? rlog[b * NSEG + wid * 32 + lane] : 0.f;
    #pragma unroll
    for (int off = 32; off > 0; off >>= 1) rls += __shfl_xor(rls, off, 64);

    const int jj = (lane < NK) ? lane : NK - 1;

#define RL(v, k) __uint_as_float(__builtin_amdgcn_readlane(__float_as_uint(v), k))

    float a, csum = 0.f, Orenorm = 0.f;
    float ncur[21], nnx[21];

    if (wid == 0) {
        // csum over t in [0, min(256,L))
        const int hi = (L < 256) ? L : 256;
        for (int t = lane; t < hi; t += 64) csum += lg[t * NK];
        // alpha_0
        a = __expf(start_t[jj]) * __expf(lg[jj] - lg[0]);

        const float* base = Ncol + (size_t)b * NSEG * 441 + jj * 21;
        #pragma unroll
        for (int k = 0; k < 21; ++k) ncur[k] = base[k];
        for (int s = 0; s < 32; ++s) {
            if (s < 31) {
                const float* p = base + (size_t)(s + 1) * 441;
                #pragma unroll
                for (int k = 0; k < 21; ++k) nnx[k] = p[k];
            }
            float s0 = RL(a, 0) * ncur[0];
            float s1 = RL(a, 1) * ncur[1];
            float s2 = RL(a, 2) * ncur[2];
            #pragma unroll
            for (int k = 3; k < 21; k += 3) {
                s0 = fmaf(RL(a, k    ), ncur[k    ], s0);
                s1 = fmaf(RL(a, k + 1), ncur[k + 1], s1);
                s2 = fmaf(RL(a, k + 2), ncur[k + 2], s2);
            }
            a = (s0 + s1) + s2;
            const float m = __uint_as_float(
                __builtin_amdgcn_readfirstlane(__float_as_uint(a)));
            a *= __builtin_amdgcn_rcpf(m);
            Orenorm += __logf(m);
            if (s < 31) {
                #pragma unroll
                for (int k = 0; k < 21; ++k) ncur[k] = nnx[k];
            }
        }
    } else {
        // csum over t in [256, L)
        for (int t = 256 + lane; t < L; t += 64) csum += lg[t * NK];
        a = __expf(end_t[jj]);                   // beta after t=L-1

        const float* base = Nrow + (size_t)b * NSEG * 441 + jj * 21;
        #pragma unroll
        for (int k = 0; k < 21; ++k) ncur[k] = base[(size_t)63 * 441 + k];
        for (int s = 63; s >= 32; --s) {
            if (s > 32) {
                const float* p = base + (size_t)(s - 1) * 441;
                #pragma unroll
                for (int k = 0; k < 21; ++k) nnx[k] = p[k];
            }
            float s0 = RL(a, 0) * ncur[0];
            float s1 = RL(a, 1) * ncur[1];
            float s2 = RL(a, 2) * ncur[2];
            #pragma unroll
            for (int k = 3; k < 21; k += 3) {
                s0 = fmaf(RL(a, k    ), ncur[k    ], s0);
                s1 = fmaf(RL(a, k + 1), ncur[k + 1], s1);
                s2 = fmaf(RL(a, k + 2), ncur[k + 2], s2);
            }
            a = (s0 + s1) + s2;
            const float m = __uint_as_float(
                __builtin_amdgcn_readfirstlane(__float_as_uint(a)));
            a *= __builtin_amdgcn_rcpf(m);
            Orenorm += __logf(m);
            if (s > 32) {
                #pragma unroll
                for (int k = 0; k < 21; ++k) ncur[k] = nnx[k];
            }
        }
    }
#undef RL

    #pragma unroll
    for (int off = 32; off > 0; off >>= 1) csum += __shfl_xor(csum, off, 64);

    if (wid == 1) {
        if (lane < NK) comb[lane] = a;           // beta_m
        if (lane == 0) comb[21] = csum + Orenorm + rls;
    }
    __syncthreads();

    if (wid == 0) {
        float val = (lane < NK) ? a * comb[lane] : 0.f;
        #pragma unroll
        for (int off = 32; off > 0; off >>= 1) val += __shfl_xor(val, off, 64);
        if (lane == 0) {
            const float OF  = csum + Orenorm + rls;
            const float num = comb[22] + comb[23];
            per_batch[b] = OF + comb[21] + __logf(val) - num;
        }
    }
}

// ---------------- final reduce: nll = sum_b (logZ_b - num_b) ----------------
__global__ __launch_bounds__(64) void reduce_kernel(
    const float* __restrict__ pb, float* __restrict__ out)
{
    float v = pb[threadIdx.x];
    #pragma unroll
    for (int off = 32; off > 0; off >>= 1) v += __shfl_xor(v, off, 64);
    if (threadIdx.x == 0) out[BSZ * SEQ * NK] = v;
}

extern "C" void kernel_launch(void* const* d_in, const int* in_sizes, int n_in,
                              void* d_out, int out_size, void* d_ws, size_t ws_size,
                              hipStream_t stream)
{
    const float* hidden  = (const float*)d_in[0];
    const float* W       = (const float*)d_in[1];
    const float* bias    = (const float*)d_in[2];
    const float* start_t = (const float*)d_in[3];
    const float* trans   = (const float*)d_in[4];
    const float* end_t   = (const float*)d_in[5];
    const int*   labels  = (const int*)d_in[6];
    const int*   mask    = (const int*)d_in[7];
    float* out = (float*)d_out;

    unsigned short* WT = (unsigned short*)d_ws;                // 48 KB
    float* f    = (float*)((char*)d_ws + 65536);
    float* pb   = f;                                           // 64
    float* rlog = f + 64;                                      // 4096
    float* Nrow = f + 8192;                                    // 64*64*441
    float* Ncol = Nrow + BSZ * NSEG * 441;                     // 64*64*441

    wconv_kernel<<<(32 * HID) / 256, 256, 0, stream>>>(W, WT);
    gemm_bias_kernel<<<(BSZ * SEQ) / 64, 256, 0, stream>>>(hidden, WT, bias, out);
    prepass_kernel<<<BSZ * NSEG, 64, 0, stream>>>(out, trans, mask, Nrow, Ncol, rlog);
    scan_kernel<<<BSZ, 128, 0, stream>>>(out, start_t, trans, end_t, labels, mask,
                                         Nrow, Ncol, rlog, pb);
    reduce_kernel<<<1, 64, 0, stream>>>(pb, out);
}

// Round 10
// 228.650 us; speedup vs baseline: 1.0723x; 1.0723x over previous
//
#include <hip/hip_runtime.h>

#define BSZ 64
#define SEQ 512
#define HID 768
#define NK  21
#define NSEG 32        // segments per batch
#define SEGLEN 16      // steps per segment (NSEG*SEGLEN == SEQ)
#define PSTR 448       // padded matrix stride (shorts): 896 B = 7 x 128 B

typedef short bf16x8 __attribute__((ext_vector_type(8)));
typedef float f32x4  __attribute__((ext_vector_type(4)));

__device__ __forceinline__ unsigned f2bf1(float x) {   // RNE fp32->bf16
    unsigned u = __float_as_uint(x);
    return (u + 0x7fffu + ((u >> 16) & 1u)) >> 16;
}
__device__ __forceinline__ unsigned f2bf_pk(float lo, float hi) {
    return f2bf1(lo) | (f2bf1(hi) << 16);
}
__device__ __forceinline__ float bf2f(unsigned short v) {
    return __uint_as_float(((unsigned)v) << 16);
}

// ------- W pre-convert (blocks 0..95) + per-batch lengths (block 96) --------
__global__ __launch_bounds__(256) void wconv_len_kernel(
    const float* __restrict__ W, const int* __restrict__ mask,
    unsigned short* __restrict__ WT, int* __restrict__ Lbuf)
{
    if (blockIdx.x < 96) {
        const int idx = blockIdx.x * 256 + threadIdx.x;    // 0 .. 24575
        const int n = idx / HID;
        const int k = idx - n * HID;
        unsigned short v = 0;
        if (n < NK) v = (unsigned short)f2bf1(W[(size_t)k * NK + n]);
        WT[idx] = v;
    } else {
        const int tid = threadIdx.x;
        const int b = tid >> 2, q = tid & 3;               // 4 threads per batch
        const int* msk = mask + b * SEQ + q * 128;
        int cnt = 0;
        for (int r = 0; r < 128; ++r) cnt += (msk[r] != 0);
        cnt += __shfl_xor(cnt, 1, 64);
        cnt += __shfl_xor(cnt, 2, 64);
        if (q == 0) Lbuf[b] = cnt;
    }
}

// ---------------- GEMM + bias (bf16 MFMA) — UNCHANGED from R8 ----------------
__global__ __launch_bounds__(256) void gemm_bias_kernel(
    const float* __restrict__ hidden, const unsigned short* __restrict__ WT,
    const float* __restrict__ bias, float* __restrict__ out)
{
    const int tid  = threadIdx.x;
    const int lane = tid & 63;
    const int wv   = tid >> 6;
    const int n    = lane & 15;
    const int quad = lane >> 4;

    const int arow = blockIdx.x * 64 + wv * 16 + n;
    const float* ap = hidden + (size_t)arow * HID + quad * 8;
    const bf16x8* bp0 = (const bf16x8*)(WT + (size_t)n * HID + quad * 8);
    const bf16x8* bp1 = (const bf16x8*)(WT + (size_t)(16 + n) * HID + quad * 8);

    f32x4 acc0 = {0.f, 0.f, 0.f, 0.f};
    f32x4 acc1 = {0.f, 0.f, 0.f, 0.f};

    float4 c0a = *(const float4*)(ap + 0);
    float4 c0b = *(const float4*)(ap + 4);

    #pragma unroll
    for (int c = 0; c < HID / 32; ++c) {
        float4 c1a, c1b;
        if (c + 1 < HID / 32) {
            c1a = *(const float4*)(ap + (c + 1) * 32);
            c1b = *(const float4*)(ap + (c + 1) * 32 + 4);
        }
        union { bf16x8 v; unsigned u[4]; } af;
        af.u[0] = f2bf_pk(c0a.x, c0a.y);
        af.u[1] = f2bf_pk(c0a.z, c0a.w);
        af.u[2] = f2bf_pk(c0b.x, c0b.y);
        af.u[3] = f2bf_pk(c0b.z, c0b.w);

        const bf16x8 b0 = bp0[c * 4];
        const bf16x8 b1 = bp1[c * 4];

        acc0 = __builtin_amdgcn_mfma_f32_16x16x32_bf16(af.v, b0, acc0, 0, 0, 0);
        acc1 = __builtin_amdgcn_mfma_f32_16x16x32_bf16(af.v, b1, acc1, 0, 0, 0);
        c0a = c1a; c0b = c1b;
    }

    const float b0v = bias[n];
    const float b1v = (n < NK - 16) ? bias[16 + n] : 0.f;
    const int rbase = blockIdx.x * 64 + wv * 16 + quad * 4;
    #pragma unroll
    for (int r = 0; r < 4; ++r) {
        float* op = out + (size_t)(rbase + r) * NK;
        op[n] = acc0[r] + b0v;
        if (n < NK - 16) op[16 + n] = acc1[r] + b1v;
    }
}

// ---------------- CRF pre-pass: per-segment matrix products (bf16 out) -------
// One wave per (b, s). N_s = Prod_{t=16s+1..16s+16} M_t; M_t = E*diag(X_t),
// identity for t>=L. Renorm by [0][0] each multiply; logs accumulated.
__global__ __launch_bounds__(64) void prepass_kernel(
    const float* __restrict__ logits, const float* __restrict__ trans,
    const int* __restrict__ Lbuf,
    unsigned short* __restrict__ Nrowb, unsigned short* __restrict__ Ncolb,
    float* __restrict__ rlog)
{
    const int bs   = blockIdx.x;                 // b*NSEG + s
    const int b    = bs >> 5;
    const int s    = bs & 31;
    const int lane = threadIdx.x;
    int g = lane / 21; if (g > 2) g = 2;         // lane 63 duplicates (20,2)
    int i = lane - g * 21; if (i > 20) i = 20;
    const int j0 = 7 * g;

    const int L = Lbuf[b];

    float E[21][7];                              // E[k][j] for this lane's cols
    #pragma unroll
    for (int k = 0; k < 21; ++k)
        #pragma unroll
        for (int jl = 0; jl < 7; ++jl)
            E[k][jl] = __expf(trans[k * NK + j0 + jl]);

    const float* lg = logits + (size_t)b * SEQ * NK;

    float P[7];
    float rl = 0.f;
    const int t0 = s * SEGLEN + 1;

    if (t0 < L) {                                // P := M_{t0}
        const float C = lg[t0 * NK];
        #pragma unroll
        for (int jl = 0; jl < 7; ++jl)
            P[jl] = E[i][jl] * __expf(lg[t0 * NK + j0 + jl] - C);
    } else {                                     // identity
        #pragma unroll
        for (int jl = 0; jl < 7; ++jl) P[jl] = (i == j0 + jl) ? 1.f : 0.f;
    }

#define BPF(v, idx) __uint_as_float(__builtin_amdgcn_ds_bpermute((idx) * 4, __float_as_uint(v)))

    #pragma unroll
    for (int u = 1; u < SEGLEN; ++u) {
        const int t = t0 + u;
        if (t < L) {                             // wave-uniform branch
            float row[21];                       // row i of current P
            #pragma unroll
            for (int k = 0; k < 21; ++k)
                row[k] = BPF(P[k % 7], (k / 7) * 21 + i);

            const float C = lg[t * NK];
            float X[7];
            #pragma unroll
            for (int jl = 0; jl < 7; ++jl)
                X[jl] = __expf(lg[t * NK + j0 + jl] - C);

            #pragma unroll
            for (int jl = 0; jl < 7; ++jl) {
                float s0 = row[0] * E[0][jl];
                float s1 = row[1] * E[1][jl];
                float s2 = row[2] * E[2][jl];
                #pragma unroll
                for (int k = 3; k < 21; k += 3) {
                    s0 = fmaf(row[k    ], E[k    ][jl], s0);
                    s1 = fmaf(row[k + 1], E[k + 1][jl], s1);
                    s2 = fmaf(row[k + 2], E[k + 2][jl], s2);
                }
                P[jl] = ((s0 + s1) + s2) * X[jl];
            }
            const float m = BPF(P[0], 0);        // entry [0][0]
            const float r = __builtin_amdgcn_rcpf(m);
            #pragma unroll
            for (int jl = 0; jl < 7; ++jl) P[jl] *= r;
            rl += __logf(m);
        }
    }
#undef BPF

    if (lane < 63) {                             // lane 63 is a duplicate
        unsigned short* nr = Nrowb + (size_t)bs * PSTR + i * 21 + j0;
        #pragma unroll
        for (int jl = 0; jl < 7; ++jl) nr[jl] = (unsigned short)f2bf1(P[jl]);
        unsigned short* nc = Ncolb + (size_t)bs * PSTR + i;
        #pragma unroll
        for (int jl = 0; jl < 7; ++jl)
            nc[(j0 + jl) * 21] = (unsigned short)f2bf1(P[jl]);
    }
    if (lane == 0) rlog[bs] = rl;
}

// ---------------- CRF scan: 16 matrix-vector steps per wave ------------------
__global__ __launch_bounds__(128) void scan_kernel(
    const float* __restrict__ logits,
    const float* __restrict__ start_t,
    const float* __restrict__ trans,
    const float* __restrict__ end_t,
    const int* __restrict__ labels,
    const int* __restrict__ Lbuf,
    const unsigned short* __restrict__ Nrowb,
    const unsigned short* __restrict__ Ncolb,
    const float* __restrict__ rlog,
    float* __restrict__ per_batch)
{
    __shared__ float comb[26];                   // [0..20] beta_m, [21] OB, [22/23] num

    const int b    = blockIdx.x;
    const int tid  = threadIdx.x;
    const int lane = tid & 63;
    const int wid  = tid >> 6;                   // 0 = forward, 1 = backward

    const float* lg = logits + (size_t)b * SEQ * NK;
    const int* lab = labels + b * SEQ;
    const int L = Lbuf[b];

    {   // numerator partials over 128 threads
        float numacc = 0.f;
        for (int t = tid; t < L; t += 128) {
            if (t == 0) numacc += start_t[lab[0]] + lg[lab[0]];
            else        numacc += lg[t * NK + lab[t]] + trans[lab[t - 1] * NK + lab[t]];
        }
        if (tid == 0) numacc += end_t[lab[L - 1]];
        #pragma unroll
        for (int off = 32; off > 0; off >>= 1) numacc += __shfl_xor(numacc, off, 64);
        if (lane == 0) comb[22 + wid] = numacc;
    }

    // rlog partial: fwd sums s=0..15, bwd s=16..31
    float rls = (lane < 16) ? rlog[b * NSEG + wid * 16 + lane] : 0.f;
    #pragma unroll
    for (int off = 32; off > 0; off >>= 1) rls += __shfl_xor(rls, off, 64);

    const int jj = (lane < NK) ? lane : NK - 1;

#define RL(v, k) __uint_as_float(__builtin_amdgcn_readlane(__float_as_uint(v), k))

    float a, csum = 0.f, Orenorm = 0.f;
    float ncur[21], nnx[21];

    if (wid == 0) {
        // csum over t in [0, 256)  (L >= 256 always)
        for (int t = lane; t < 256; t += 64) csum += lg[t * NK];
        a = __expf(start_t[jj]) * __expf(lg[jj] - lg[0]);   // alpha_0

        const unsigned short* base = Ncolb + (size_t)b * NSEG * PSTR + jj * 21;
        #pragma unroll
        for (int k = 0; k < 21; ++k) ncur[k] = bf2f(base[k]);
        for (int s = 0; s < 16; ++s) {
            if (s < 15) {
                const unsigned short* p = base + (size_t)(s + 1) * PSTR;
                #pragma unroll
                for (int k = 0; k < 21; ++k) nnx[k] = bf2f(p[k]);
            }
            float s0 = RL(a, 0) * ncur[0];
            float s1 = RL(a, 1) * ncur[1];
            float s2 = RL(a, 2) * ncur[2];
            #pragma unroll
            for (int k = 3; k < 21; k += 3) {
                s0 = fmaf(RL(a, k    ), ncur[k    ], s0);
                s1 = fmaf(RL(a, k + 1), ncur[k + 1], s1);
                s2 = fmaf(RL(a, k + 2), ncur[k + 2], s2);
            }
            a = (s0 + s1) + s2;
            const float m = __uint_as_float(
                __builtin_amdgcn_readfirstlane(__float_as_uint(a)));
            a *= __builtin_amdgcn_rcpf(m);
            Orenorm += __logf(m);
            if (s < 15) {
                #pragma unroll
                for (int k = 0; k < 21; ++k) ncur[k] = nnx[k];
            }
        }
    } else {
        // csum over t in [256, L)
        for (int t = 256 + lane; t < L; t += 64) csum += lg[t * NK];
        a = __expf(end_t[jj]);                   // beta at t = L-1

        const unsigned short* base = Nrowb + (size_t)b * NSEG * PSTR + jj * 21;
        #pragma unroll
        for (int k = 0; k < 21; ++k) ncur[k] = bf2f(base[(size_t)31 * PSTR + k]);
        for (int s = 31; s >= 16; --s) {
            if (s > 16) {
                const unsigned short* p = base + (size_t)(s - 1) * PSTR;
                #pragma unroll
                for (int k = 0; k < 21; ++k) nnx[k] = bf2f(p[k]);
            }
            float s0 = RL(a, 0) * ncur[0];
            float s1 = RL(a, 1) * ncur[1];
            float s2 = RL(a, 2) * ncur[2];
            #pragma unroll
            for (int k = 3; k < 21; k += 3) {
                s0 = fmaf(RL(a, k    ), ncur[k    ], s0);
                s1 = fmaf(RL(a, k + 1), ncur[k + 1], s1);
                s2 = fmaf(RL(a, k + 2), ncur[k + 2], s2);
            }
            a = (s0 + s1) + s2;
            const float m = __uint_as_float(
                __builtin_amdgcn_readfirstlane(__float_as_uint(a)));
            a *= __builtin_amdgcn_rcpf(m);
            Orenorm += __logf(m);
            if (s > 16) {
                #pragma unroll
                for (int k = 0; k < 21; ++k) ncur[k] = nnx[k];
            }
        }
    }
#undef RL

    #pragma unroll
    for (int off = 32; off > 0; off >>= 1) csum += __shfl_xor(csum, off, 64);

    if (wid == 1) {
        if (lane < NK) comb[lane] = a;           // beta_m
        if (lane == 0) comb[21] = csum + Orenorm + rls;
    }
    __syncthreads();

    if (wid == 0) {
        float val = (lane < NK) ? a * comb[lane] : 0.f;
        #pragma unroll
        for (int off = 32; off > 0; off >>= 1) val += __shfl_xor(val, off, 64);
        if (lane == 0) {
            const float OF  = csum + Orenorm + rls;
            const float num = comb[22] + comb[23];
            per_batch[b] = OF + comb[21] + __logf(val) - num;
        }
    }
}

// ---------------- final reduce: nll = sum_b (logZ_b - num_b) ----------------
__global__ __launch_bounds__(64) void reduce_kernel(
    const float* __restrict__ pb, float* __restrict__ out)
{
    float v = pb[threadIdx.x];
    #pragma unroll
    for (int off = 32; off > 0; off >>= 1) v += __shfl_xor(v, off, 64);
    if (threadIdx.x == 0) out[BSZ * SEQ * NK] = v;
}

extern "C" void kernel_launch(void* const* d_in, const int* in_sizes, int n_in,
                              void* d_out, int out_size, void* d_ws, size_t ws_size,
                              hipStream_t stream)
{
    const float* hidden  = (const float*)d_in[0];
    const float* W       = (const float*)d_in[1];
    const float* bias    = (const float*)d_in[2];
    const float* start_t = (const float*)d_in[3];
    const float* trans   = (const float*)d_in[4];
    const float* end_t   = (const float*)d_in[5];
    const int*   labels  = (const int*)d_in[6];
    const int*   mask    = (const int*)d_in[7];
    float* out = (float*)d_out;

    char* ws = (char*)d_ws;
    unsigned short* WT    = (unsigned short*)ws;               // 48 KB
    float*          pb    = (float*)(ws + 65536);              // 64 f
    int*            Lbuf  = (int*)(ws + 66560);                // 64 i
    float*          rlog  = (float*)(ws + 69632);              // 2048 f
    unsigned short* Nrowb = (unsigned short*)(ws + 131072);    // 2048*448 bf16
    unsigned short* Ncolb = (unsigned short*)(ws + 131072 + 2097152);

    wconv_len_kernel<<<97, 256, 0, stream>>>(W, mask, WT, Lbuf);
    gemm_bias_kernel<<<(BSZ * SEQ) / 64, 256, 0, stream>>>(hidden, WT, bias, out);
    prepass_kernel<<<BSZ * NSEG, 64, 0, stream>>>(out, trans, Lbuf, Nrowb, Ncolb, rlog);
    scan_kernel<<<BSZ, 128, 0, stream>>>(out, start_t, trans, end_t, labels, Lbuf,
                                         Nrowb, Ncolb, rlog, pb);
    reduce_kernel<<<1, 64, 0, stream>>>(pb, out);
}

// Round 11
// 209.637 us; speedup vs baseline: 1.1695x; 1.0907x over previous
//
#include <hip/hip_runtime.h>

#define BSZ 64
#define SEQ 512
#define HID 768
#define NK  21
#define NSEG 32        // segments per batch
#define SEGLEN 16      // steps per segment (NSEG*SEGLEN == SEQ)
#define PSTR 448       // padded matrix stride (shorts): 896 B = 7 x 128 B

typedef short bf16x8 __attribute__((ext_vector_type(8)));
typedef float f32x4  __attribute__((ext_vector_type(4)));

__device__ __forceinline__ unsigned f2bf1(float x) {   // RNE fp32->bf16
    unsigned u = __float_as_uint(x);
    return (u + 0x7fffu + ((u >> 16) & 1u)) >> 16;
}
__device__ __forceinline__ unsigned f2bf_pk(float lo, float hi) {
    return f2bf1(lo) | (f2bf1(hi) << 16);
}
__device__ __forceinline__ float bf2f(unsigned short v) {
    return __uint_as_float(((unsigned)v) << 16);
}

// ------- W pre-convert (blocks 0..95) + per-batch lengths (block 96) --------
__global__ __launch_bounds__(256) void wconv_len_kernel(
    const float* __restrict__ W, const int* __restrict__ mask,
    unsigned short* __restrict__ WT, int* __restrict__ Lbuf)
{
    if (blockIdx.x < 96) {
        const int idx = blockIdx.x * 256 + threadIdx.x;    // 0 .. 24575
        const int n = idx / HID;
        const int k = idx - n * HID;
        unsigned short v = 0;
        if (n < NK) v = (unsigned short)f2bf1(W[(size_t)k * NK + n]);
        WT[idx] = v;
    } else {
        const int tid = threadIdx.x;
        const int b = tid >> 2, q = tid & 3;               // 4 threads per batch
        const int* msk = mask + b * SEQ + q * 128;
        int cnt = 0;
        for (int r = 0; r < 128; ++r) cnt += (msk[r] != 0);
        cnt += __shfl_xor(cnt, 1, 64);
        cnt += __shfl_xor(cnt, 2, 64);
        if (q == 0) Lbuf[b] = cnt;
    }
}

// ---------------- GEMM + bias (bf16 MFMA) — UNCHANGED from R8 ----------------
__global__ __launch_bounds__(256) void gemm_bias_kernel(
    const float* __restrict__ hidden, const unsigned short* __restrict__ WT,
    const float* __restrict__ bias, float* __restrict__ out)
{
    const int tid  = threadIdx.x;
    const int lane = tid & 63;
    const int wv   = tid >> 6;
    const int n    = lane & 15;
    const int quad = lane >> 4;

    const int arow = blockIdx.x * 64 + wv * 16 + n;
    const float* ap = hidden + (size_t)arow * HID + quad * 8;
    const bf16x8* bp0 = (const bf16x8*)(WT + (size_t)n * HID + quad * 8);
    const bf16x8* bp1 = (const bf16x8*)(WT + (size_t)(16 + n) * HID + quad * 8);

    f32x4 acc0 = {0.f, 0.f, 0.f, 0.f};
    f32x4 acc1 = {0.f, 0.f, 0.f, 0.f};

    float4 c0a = *(const float4*)(ap + 0);
    float4 c0b = *(const float4*)(ap + 4);

    #pragma unroll
    for (int c = 0; c < HID / 32; ++c) {
        float4 c1a, c1b;
        if (c + 1 < HID / 32) {
            c1a = *(const float4*)(ap + (c + 1) * 32);
            c1b = *(const float4*)(ap + (c + 1) * 32 + 4);
        }
        union { bf16x8 v; unsigned u[4]; } af;
        af.u[0] = f2bf_pk(c0a.x, c0a.y);
        af.u[1] = f2bf_pk(c0a.z, c0a.w);
        af.u[2] = f2bf_pk(c0b.x, c0b.y);
        af.u[3] = f2bf_pk(c0b.z, c0b.w);

        const bf16x8 b0 = bp0[c * 4];
        const bf16x8 b1 = bp1[c * 4];

        acc0 = __builtin_amdgcn_mfma_f32_16x16x32_bf16(af.v, b0, acc0, 0, 0, 0);
        acc1 = __builtin_amdgcn_mfma_f32_16x16x32_bf16(af.v, b1, acc1, 0, 0, 0);
        c0a = c1a; c0b = c1b;
    }

    const float b0v = bias[n];
    const float b1v = (n < NK - 16) ? bias[16 + n] : 0.f;
    const int rbase = blockIdx.x * 64 + wv * 16 + quad * 4;
    #pragma unroll
    for (int r = 0; r < 4; ++r) {
        float* op = out + (size_t)(rbase + r) * NK;
        op[n] = acc0[r] + b0v;
        if (n < NK - 16) op[16 + n] = acc1[r] + b1v;
    }
}

// ---------------- CRF pre-pass: per-segment matrix products (bf16 out) -------
// One wave per (b, s). N_s = Prod_{t=16s+1..16s+16} M_t; M_t = E*diag(X_t),
// identity for t>=L. E held PACKED bf16 (77 VGPRs, not 147 fp32 -> no scratch
// spill; R10's 79 MB WRITE_SIZE was exactly the 64lane*147*4B E spill).
// All Epk indices compile-time constant. Renorm by [0][0] each multiply.
#define EHI(u) __uint_as_float((u) & 0xffff0000u)
#define ELO(u) __uint_as_float((u) << 16)
__global__ __launch_bounds__(64, 2) void prepass_kernel(
    const float* __restrict__ logits, const float* __restrict__ trans,
    const int* __restrict__ Lbuf,
    unsigned short* __restrict__ Nrowb, unsigned short* __restrict__ Ncolb,
    float* __restrict__ rlog)
{
    const int bs   = blockIdx.x;                 // b*NSEG + s
    const int b    = bs >> 5;
    const int s    = bs & 31;
    const int lane = threadIdx.x;
    int g = lane / 21; if (g > 2) g = 2;         // lane 63 duplicates (20,2)
    int i = lane - g * 21; if (i > 20) i = 20;
    const int j0 = 7 * g;

    const int L = Lbuf[b];

    // Epk[jl][p]: bf16(E[2p][j0+jl]) in high16, bf16(E[2p+1][j0+jl]) in low16
    unsigned Epk[7][11];
    #pragma unroll
    for (int jl = 0; jl < 7; ++jl)
        #pragma unroll
        for (int p = 0; p < 11; ++p) {
            const float ehi = __expf(trans[(2 * p) * NK + j0 + jl]);
            const float elo = (2 * p + 1 < 21)
                            ? __expf(trans[(2 * p + 1) * NK + j0 + jl]) : 0.f;
            Epk[jl][p] = (f2bf1(ehi) << 16) | f2bf1(elo);
        }

    const float* lg = logits + (size_t)b * SEQ * NK;

    float P[7];
    float rl = 0.f;
    const int t0 = s * SEGLEN + 1;

    if (t0 < L) {                                // P := M_{t0} (fresh exp for E row i)
        const float C = lg[t0 * NK];
        #pragma unroll
        for (int jl = 0; jl < 7; ++jl)
            P[jl] = __expf(trans[i * NK + j0 + jl])
                  * __expf(lg[t0 * NK + j0 + jl] - C);
    } else {                                     // identity
        #pragma unroll
        for (int jl = 0; jl < 7; ++jl) P[jl] = (i == j0 + jl) ? 1.f : 0.f;
    }

#define BPF(v, idx) __uint_as_float(__builtin_amdgcn_ds_bpermute((idx) * 4, __float_as_uint(v)))

    #pragma unroll
    for (int u = 1; u < SEGLEN; ++u) {
        const int t = t0 + u;
        if (t < L) {                             // wave-uniform branch
            float row[22];                       // row i of current P (+ zero pad)
            #pragma unroll
            for (int k = 0; k < 21; ++k)
                row[k] = BPF(P[k % 7], (k / 7) * 21 + i);
            row[21] = 0.f;

            const float C = lg[t * NK];
            float X[7];
            #pragma unroll
            for (int jl = 0; jl < 7; ++jl)
                X[jl] = __expf(lg[t * NK + j0 + jl] - C);

            #pragma unroll
            for (int jl = 0; jl < 7; ++jl) {
                float s0 = 0.f, s1 = 0.f;
                #pragma unroll
                for (int p = 0; p < 11; ++p) {
                    const unsigned e = Epk[jl][p];
                    s0 = fmaf(row[2 * p    ], EHI(e), s0);
                    s1 = fmaf(row[2 * p + 1], ELO(e), s1);
                }
                P[jl] = (s0 + s1) * X[jl];
            }
            const float m = BPF(P[0], 0);        // entry [0][0]
            const float r = __builtin_amdgcn_rcpf(m);
            #pragma unroll
            for (int jl = 0; jl < 7; ++jl) P[jl] *= r;
            rl += __logf(m);
        }
    }
#undef BPF

    if (lane < 63) {                             // lane 63 is a duplicate
        unsigned short* nr = Nrowb + (size_t)bs * PSTR + i * 21 + j0;
        #pragma unroll
        for (int jl = 0; jl < 7; ++jl) nr[jl] = (unsigned short)f2bf1(P[jl]);
        unsigned short* nc = Ncolb + (size_t)bs * PSTR + i;
        #pragma unroll
        for (int jl = 0; jl < 7; ++jl)
            nc[(j0 + jl) * 21] = (unsigned short)f2bf1(P[jl]);
    }
    if (lane == 0) rlog[bs] = rl;
}

// ---------------- CRF scan: 16 matrix-vector steps per wave ------------------
__global__ __launch_bounds__(128) void scan_kernel(
    const float* __restrict__ logits,
    const float* __restrict__ start_t,
    const float* __restrict__ trans,
    const float* __restrict__ end_t,
    const int* __restrict__ labels,
    const int* __restrict__ Lbuf,
    const unsigned short* __restrict__ Nrowb,
    const unsigned short* __restrict__ Ncolb,
    const float* __restrict__ rlog,
    float* __restrict__ per_batch)
{
    __shared__ float comb[26];                   // [0..20] beta_m, [21] OB, [22/23] num

    const int b    = blockIdx.x;
    const int tid  = threadIdx.x;
    const int lane = tid & 63;
    const int wid  = tid >> 6;                   // 0 = forward, 1 = backward

    const float* lg = logits + (size_t)b * SEQ * NK;
    const int* lab = labels + b * SEQ;
    const int L = Lbuf[b];

    {   // numerator partials over 128 threads
        float numacc = 0.f;
        for (int t = tid; t < L; t += 128) {
            if (t == 0) numacc += start_t[lab[0]] + lg[lab[0]];
            else        numacc += lg[t * NK + lab[t]] + trans[lab[t - 1] * NK + lab[t]];
        }
        if (tid == 0) numacc += end_t[lab[L - 1]];
        #pragma unroll
        for (int off = 32; off > 0; off >>= 1) numacc += __shfl_xor(numacc, off, 64);
        if (lane == 0) comb[22 + wid] = numacc;
    }

    // rlog partial: fwd sums s=0..15, bwd s=16..31
    float rls = (lane < 16) ? rlog[b * NSEG + wid * 16 + lane] : 0.f;
    #pragma unroll
    for (int off = 32; off > 0; off >>= 1) rls += __shfl_xor(rls, off, 64);

    const int jj = (lane < NK) ? lane : NK - 1;

#define RL(v, k) __uint_as_float(__builtin_amdgcn_readlane(__float_as_uint(v), k))

    float a, csum = 0.f, Orenorm = 0.f;
    float ncur[21], nnx[21];

    if (wid == 0) {
        // csum over t in [0, 256)  (L >= 256 always)
        for (int t = lane; t < 256; t += 64) csum += lg[t * NK];
        a = __expf(start_t[jj]) * __expf(lg[jj] - lg[0]);   // alpha_0

        const unsigned short* base = Ncolb + (size_t)b * NSEG * PSTR + jj * 21;
        #pragma unroll
        for (int k = 0; k < 21; ++k) ncur[k] = bf2f(base[k]);
        for (int s = 0; s < 16; ++s) {
            if (s < 15) {
                const unsigned short* p = base + (size_t)(s + 1) * PSTR;
                #pragma unroll
                for (int k = 0; k < 21; ++k) nnx[k] = bf2f(p[k]);
            }
            float s0 = RL(a, 0) * ncur[0];
            float s1 = RL(a, 1) * ncur[1];
            float s2 = RL(a, 2) * ncur[2];
            #pragma unroll
            for (int k = 3; k < 21; k += 3) {
                s0 = fmaf(RL(a, k    ), ncur[k    ], s0);
                s1 = fmaf(RL(a, k + 1), ncur[k + 1], s1);
                s2 = fmaf(RL(a, k + 2), ncur[k + 2], s2);
            }
            a = (s0 + s1) + s2;
            const float m = __uint_as_float(
                __builtin_amdgcn_readfirstlane(__float_as_uint(a)));
            a *= __builtin_amdgcn_rcpf(m);
            Orenorm += __logf(m);
            if (s < 15) {
                #pragma unroll
                for (int k = 0; k < 21; ++k) ncur[k] = nnx[k];
            }
        }
    } else {
        // csum over t in [256, L)
        for (int t = 256 + lane; t < L; t += 64) csum += lg[t * NK];
        a = __expf(end_t[jj]);                   // beta at t = L-1

        const unsigned short* base = Nrowb + (size_t)b * NSEG * PSTR + jj * 21;
        #pragma unroll
        for (int k = 0; k < 21; ++k) ncur[k] = bf2f(base[(size_t)31 * PSTR + k]);
        for (int s = 31; s >= 16; --s) {
            if (s > 16) {
                const unsigned short* p = base + (size_t)(s - 1) * PSTR;
                #pragma unroll
                for (int k = 0; k < 21; ++k) nnx[k] = bf2f(p[k]);
            }
            float s0 = RL(a, 0) * ncur[0];
            float s1 = RL(a, 1) * ncur[1];
            float s2 = RL(a, 2) * ncur[2];
            #pragma unroll
            for (int k = 3; k < 21; k += 3) {
                s0 = fmaf(RL(a, k    ), ncur[k    ], s0);
                s1 = fmaf(RL(a, k + 1), ncur[k + 1], s1);
                s2 = fmaf(RL(a, k + 2), ncur[k + 2], s2);
            }
            a = (s0 + s1) + s2;
            const float m = __uint_as_float(
                __builtin_amdgcn_readfirstlane(__float_as_uint(a)));
            a *= __builtin_amdgcn_rcpf(m);
            Orenorm += __logf(m);
            if (s > 16) {
                #pragma unroll
                for (int k = 0; k < 21; ++k) ncur[k] = nnx[k];
            }
        }
    }
#undef RL

    #pragma unroll
    for (int off = 32; off > 0; off >>= 1) csum += __shfl_xor(csum, off, 64);

    if (wid == 1) {
        if (lane < NK) comb[lane] = a;           // beta_m
        if (lane == 0) comb[21] = csum + Orenorm + rls;
    }
    __syncthreads();

    if (wid == 0) {
        float val = (lane < NK) ? a * comb[lane] : 0.f;
        #pragma unroll
        for (int off = 32; off > 0; off >>= 1) val += __shfl_xor(val, off, 64);
        if (lane == 0) {
            const float OF  = csum + Orenorm + rls;
            const float num = comb[22] + comb[23];
            per_batch[b] = OF + comb[21] + __logf(val) - num;
        }
    }
}

// ---------------- final reduce: nll = sum_b (logZ_b - num_b) ----------------
__global__ __launch_bounds__(64) void reduce_kernel(
    const float* __restrict__ pb, float* __restrict__ out)
{
    float v = pb[threadIdx.x];
    #pragma unroll
    for (int off = 32; off > 0; off >>= 1) v += __shfl_xor(v, off, 64);
    if (threadIdx.x == 0) out[BSZ * SEQ * NK] = v;
}

extern "C" void kernel_launch(void* const* d_in, const int* in_sizes, int n_in,
                              void* d_out, int out_size, void* d_ws, size_t ws_size,
                              hipStream_t stream)
{
    const float* hidden  = (const float*)d_in[0];
    const float* W       = (const float*)d_in[1];
    const float* bias    = (const float*)d_in[2];
    const float* start_t = (const float*)d_in[3];
    const float* trans   = (const float*)d_in[4];
    const float* end_t   = (const float*)d_in[5];
    const int*   labels  = (const int*)d_in[6];
    const int*   mask    = (const int*)d_in[7];
    float* out = (float*)d_out;

    char* ws = (char*)d_ws;
    unsigned short* WT    = (unsigned short*)ws;               // 48 KB
    float*          pb    = (float*)(ws + 65536);              // 64 f
    int*            Lbuf  = (int*)(ws + 66560);                // 64 i
    float*          rlog  = (float*)(ws + 69632);              // 2048 f
    unsigned short* Nrowb = (unsigned short*)(ws + 131072);    // 2048*448 bf16
    unsigned short* Ncolb = (unsigned short*)(ws + 131072 + 2097152);

    wconv_len_kernel<<<97, 256, 0, stream>>>(W, mask, WT, Lbuf);
    gemm_bias_kernel<<<(BSZ * SEQ) / 64, 256, 0, stream>>>(hidden, WT, bias, out);
    prepass_kernel<<<BSZ * NSEG, 64, 0, stream>>>(out, trans, Lbuf, Nrowb, Ncolb, rlog);
    scan_kernel<<<BSZ, 128, 0, stream>>>(out, start_t, trans, end_t, labels, Lbuf,
                                         Nrowb, Ncolb, rlog, pb);
    reduce_kernel<<<1, 64, 0, stream>>>(pb, out);
}

// Round 12
// 204.644 us; speedup vs baseline: 1.1981x; 1.0244x over previous
//
#include <hip/hip_runtime.h>

#define BSZ 64
#define SEQ 512
#define HID 768
#define NK  21
#define NSEG 32        // segments per batch
#define SEGLEN 16      // steps per segment (NSEG*SEGLEN == SEQ)
#define PSTR 512       // padded matrix stride in shorts (rows padded to 24; 1 KB/matrix)

typedef short bf16x8 __attribute__((ext_vector_type(8)));
typedef float f32x4  __attribute__((ext_vector_type(4)));

__device__ __forceinline__ unsigned f2bf1(float x) {   // RNE fp32->bf16
    unsigned u = __float_as_uint(x);
    return (u + 0x7fffu + ((u >> 16) & 1u)) >> 16;
}
__device__ __forceinline__ unsigned f2bf_pk(float lo, float hi) {
    return f2bf1(lo) | (f2bf1(hi) << 16);
}

// unpack bf16 pair packed in a dword (memory order: low short = even index)
#define U16L(d) __uint_as_float(((unsigned)(d)) << 16)
#define U16H(d) __uint_as_float(((unsigned)(d)) & 0xffff0000u)

// ------- W pre-convert (blocks 0..95) + per-batch lengths (block 96) --------
// Block 96 also zero-inits the nll output slot (scan atomicAdds into it).
__global__ __launch_bounds__(256) void wconv_len_kernel(
    const float* __restrict__ W, const int* __restrict__ mask,
    unsigned short* __restrict__ WT, int* __restrict__ Lbuf,
    float* __restrict__ out)
{
    if (blockIdx.x < 96) {
        const int idx = blockIdx.x * 256 + threadIdx.x;    // 0 .. 24575
        const int n = idx / HID;
        const int k = idx - n * HID;
        unsigned short v = 0;
        if (n < NK) v = (unsigned short)f2bf1(W[(size_t)k * NK + n]);
        WT[idx] = v;
    } else {
        const int tid = threadIdx.x;
        if (tid == 255) out[BSZ * SEQ * NK] = 0.f;         // nll accumulator
        const int b = tid >> 2, q = tid & 3;               // 4 threads per batch
        const int* msk = mask + b * SEQ + q * 128;
        int cnt = 0;
        for (int r = 0; r < 128; ++r) cnt += (msk[r] != 0);
        cnt += __shfl_xor(cnt, 1, 64);
        cnt += __shfl_xor(cnt, 2, 64);
        if (q == 0 && b < BSZ) Lbuf[b] = cnt;
    }
}

// ---------------- GEMM + bias (bf16 MFMA), depth-2 A / depth-1 B prefetch ----
__global__ __launch_bounds__(256) void gemm_bias_kernel(
    const float* __restrict__ hidden, const unsigned short* __restrict__ WT,
    const float* __restrict__ bias, float* __restrict__ out)
{
    const int tid  = threadIdx.x;
    const int lane = tid & 63;
    const int wv   = tid >> 6;
    const int n    = lane & 15;
    const int quad = lane >> 4;

    const int arow = blockIdx.x * 64 + wv * 16 + n;
    const float* ap = hidden + (size_t)arow * HID + quad * 8;
    const bf16x8* bp0 = (const bf16x8*)(WT + (size_t)n * HID + quad * 8);
    const bf16x8* bp1 = (const bf16x8*)(WT + (size_t)(16 + n) * HID + quad * 8);

    f32x4 acc0 = {0.f, 0.f, 0.f, 0.f};
    f32x4 acc1 = {0.f, 0.f, 0.f, 0.f};

    // prefetch: A chunks 0,1; B chunk 0
    float4 a0 = *(const float4*)(ap + 0);
    float4 a1 = *(const float4*)(ap + 4);
    float4 p0 = *(const float4*)(ap + 32);
    float4 p1 = *(const float4*)(ap + 36);
    bf16x8 B0 = bp0[0];
    bf16x8 B1 = bp1[0];

    #pragma unroll
    for (int c = 0; c < HID / 32; ++c) {               // 24 K-chunks
        float4 q0, q1; bf16x8 Bn0, Bn1;
        if (c + 2 < HID / 32) {                        // A depth-2
            q0 = *(const float4*)(ap + (c + 2) * 32);
            q1 = *(const float4*)(ap + (c + 2) * 32 + 4);
        }
        if (c + 1 < HID / 32) {                        // B depth-1
            Bn0 = bp0[(c + 1) * 4];
            Bn1 = bp1[(c + 1) * 4];
        }
        union { bf16x8 v; unsigned u[4]; } af;
        af.u[0] = f2bf_pk(a0.x, a0.y);
        af.u[1] = f2bf_pk(a0.z, a0.w);
        af.u[2] = f2bf_pk(a1.x, a1.y);
        af.u[3] = f2bf_pk(a1.z, a1.w);

        acc0 = __builtin_amdgcn_mfma_f32_16x16x32_bf16(af.v, B0, acc0, 0, 0, 0);
        acc1 = __builtin_amdgcn_mfma_f32_16x16x32_bf16(af.v, B1, acc1, 0, 0, 0);

        a0 = p0; a1 = p1; p0 = q0; p1 = q1;
        B0 = Bn0; B1 = Bn1;
    }

    const float b0v = bias[n];
    const float b1v = (n < NK - 16) ? bias[16 + n] : 0.f;
    const int rbase = blockIdx.x * 64 + wv * 16 + quad * 4;
    #pragma unroll
    for (int r = 0; r < 4; ++r) {
        float* op = out + (size_t)(rbase + r) * NK;
        op[n] = acc0[r] + b0v;
        if (n < NK - 16) op[16 + n] = acc1[r] + b1v;
    }
}

// ---------------- CRF pre-pass: per-segment matrix products (bf16 out) -------
// One wave per (b, s). E held packed bf16 (no scratch spill). Output rows
// padded to 24 shorts (PSTR=512 per matrix) so scan loads dwordx4.
#define EHI(u) __uint_as_float((u) & 0xffff0000u)
#define ELO(u) __uint_as_float((u) << 16)
__global__ __launch_bounds__(64, 2) void prepass_kernel(
    const float* __restrict__ logits, const float* __restrict__ trans,
    const int* __restrict__ Lbuf,
    unsigned short* __restrict__ Nrowb, unsigned short* __restrict__ Ncolb,
    float* __restrict__ rlog)
{
    const int bs   = blockIdx.x;                 // b*NSEG + s
    const int b    = bs >> 5;
    const int s    = bs & 31;
    const int lane = threadIdx.x;
    int g = lane / 21; if (g > 2) g = 2;         // lane 63 duplicates (20,2)
    int i = lane - g * 21; if (i > 20) i = 20;
    const int j0 = 7 * g;

    const int L = Lbuf[b];

    // Epk[jl][p]: bf16(E[2p][j0+jl]) high16, bf16(E[2p+1][j0+jl]) low16
    unsigned Epk[7][11];
    #pragma unroll
    for (int jl = 0; jl < 7; ++jl)
        #pragma unroll
        for (int p = 0; p < 11; ++p) {
            const float ehi = __expf(trans[(2 * p) * NK + j0 + jl]);
            const float elo = (2 * p + 1 < 21)
                            ? __expf(trans[(2 * p + 1) * NK + j0 + jl]) : 0.f;
            Epk[jl][p] = (f2bf1(ehi) << 16) | f2bf1(elo);
        }

    const float* lg = logits + (size_t)b * SEQ * NK;

    float P[7];
    float rl = 0.f;
    const int t0 = s * SEGLEN + 1;

    if (t0 < L) {                                // P := M_{t0}
        const float C = lg[t0 * NK];
        #pragma unroll
        for (int jl = 0; jl < 7; ++jl)
            P[jl] = __expf(trans[i * NK + j0 + jl])
                  * __expf(lg[t0 * NK + j0 + jl] - C);
    } else {                                     // identity
        #pragma unroll
        for (int jl = 0; jl < 7; ++jl) P[jl] = (i == j0 + jl) ? 1.f : 0.f;
    }

#define BPF(v, idx) __uint_as_float(__builtin_amdgcn_ds_bpermute((idx) * 4, __float_as_uint(v)))

    #pragma unroll
    for (int u = 1; u < SEGLEN; ++u) {
        const int t = t0 + u;
        if (t < L) {                             // wave-uniform branch
            float row[22];                       // row i of current P (+ pad)
            #pragma unroll
            for (int k = 0; k < 21; ++k)
                row[k] = BPF(P[k % 7], (k / 7) * 21 + i);
            row[21] = 0.f;

            const float C = lg[t * NK];
            float X[7];
            #pragma unroll
            for (int jl = 0; jl < 7; ++jl)
                X[jl] = __expf(lg[t * NK + j0 + jl] - C);

            #pragma unroll
            for (int jl = 0; jl < 7; ++jl) {
                float s0 = 0.f, s1 = 0.f;
                #pragma unroll
                for (int p = 0; p < 11; ++p) {
                    const unsigned e = Epk[jl][p];
                    s0 = fmaf(row[2 * p    ], EHI(e), s0);
                    s1 = fmaf(row[2 * p + 1], ELO(e), s1);
                }
                P[jl] = (s0 + s1) * X[jl];
            }
            const float m = BPF(P[0], 0);        // entry [0][0]
            const float r = __builtin_amdgcn_rcpf(m);
            #pragma unroll
            for (int jl = 0; jl < 7; ++jl) P[jl] *= r;
            rl += __logf(m);
        }
    }
#undef BPF

    if (lane < 63) {                             // lane 63 is a duplicate
        unsigned short* nr = Nrowb + (size_t)bs * PSTR + i * 24 + j0;
        #pragma unroll
        for (int jl = 0; jl < 7; ++jl) nr[jl] = (unsigned short)f2bf1(P[jl]);
        unsigned short* nc = Ncolb + (size_t)bs * PSTR + i;
        #pragma unroll
        for (int jl = 0; jl < 7; ++jl)
            nc[(j0 + jl) * 24] = (unsigned short)f2bf1(P[jl]);
    }
    if (lane == 0) rlog[bs] = rl;
}

// ---------------- CRF scan: 16 matrix-vector steps; nll via atomicAdd --------
__global__ __launch_bounds__(128) void scan_kernel(
    const float* __restrict__ logits,
    const float* __restrict__ start_t,
    const float* __restrict__ trans,
    const float* __restrict__ end_t,
    const int* __restrict__ labels,
    const int* __restrict__ Lbuf,
    const unsigned short* __restrict__ Nrowb,
    const unsigned short* __restrict__ Ncolb,
    const float* __restrict__ rlog,
    float* __restrict__ out)
{
    __shared__ float comb[26];                   // [0..20] beta_m, [21] OB, [22/23] num

    const int b    = blockIdx.x;
    const int tid  = threadIdx.x;
    const int lane = tid & 63;
    const int wid  = tid >> 6;                   // 0 = forward, 1 = backward

    const float* lg = logits + (size_t)b * SEQ * NK;
    const int* lab = labels + b * SEQ;
    const int L = Lbuf[b];

    {   // numerator partials over 128 threads
        float numacc = 0.f;
        for (int t = tid; t < L; t += 128) {
            if (t == 0) numacc += start_t[lab[0]] + lg[lab[0]];
            else        numacc += lg[t * NK + lab[t]] + trans[lab[t - 1] * NK + lab[t]];
        }
        if (tid == 0) numacc += end_t[lab[L - 1]];
        #pragma unroll
        for (int off = 32; off > 0; off >>= 1) numacc += __shfl_xor(numacc, off, 64);
        if (lane == 0) comb[22 + wid] = numacc;
    }

    // rlog partial: fwd sums s=0..15, bwd s=16..31
    float rls = (lane < 16) ? rlog[b * NSEG + wid * 16 + lane] : 0.f;
    #pragma unroll
    for (int off = 32; off > 0; off >>= 1) rls += __shfl_xor(rls, off, 64);

    const int jj = (lane < NK) ? lane : NK - 1;

#define RL(v, k) __uint_as_float(__builtin_amdgcn_readlane(__float_as_uint(v), k))
// 21-term matvec from packed bf16 row held in 3 int4 (dwords d0..d11):
#define PMV(vv, c0, c1, c2, outv) do {                                        \
    float s0 = RL(vv, 0) * U16L(c0.x);                                        \
    float s1 = RL(vv, 1) * U16H(c0.x);                                        \
    float s2 = RL(vv, 2) * U16L(c0.y);                                        \
    s0 = fmaf(RL(vv,  3), U16H(c0.y), s0); s1 = fmaf(RL(vv,  4), U16L(c0.z), s1); \
    s2 = fmaf(RL(vv,  5), U16H(c0.z), s2); s0 = fmaf(RL(vv,  6), U16L(c0.w), s0); \
    s1 = fmaf(RL(vv,  7), U16H(c0.w), s1); s2 = fmaf(RL(vv,  8), U16L(c1.x), s2); \
    s0 = fmaf(RL(vv,  9), U16H(c1.x), s0); s1 = fmaf(RL(vv, 10), U16L(c1.y), s1); \
    s2 = fmaf(RL(vv, 11), U16H(c1.y), s2); s0 = fmaf(RL(vv, 12), U16L(c1.z), s0); \
    s1 = fmaf(RL(vv, 13), U16H(c1.z), s1); s2 = fmaf(RL(vv, 14), U16L(c1.w), s2); \
    s0 = fmaf(RL(vv, 15), U16H(c1.w), s0); s1 = fmaf(RL(vv, 16), U16L(c2.x), s1); \
    s2 = fmaf(RL(vv, 17), U16H(c2.x), s2); s0 = fmaf(RL(vv, 18), U16L(c2.y), s0); \
    s1 = fmaf(RL(vv, 19), U16H(c2.y), s1); s2 = fmaf(RL(vv, 20), U16L(c2.z), s2); \
    outv = (s0 + s1) + s2;                                                    \
} while (0)

    float a, csum = 0.f, Orenorm = 0.f;
    int4 c0, c1, c2, n0, n1, n2;

    if (wid == 0) {
        // csum over t in [0, 256)  (L >= 256 always)
        for (int t = lane; t < 256; t += 64) csum += lg[t * NK];
        a = __expf(start_t[jj]) * __expf(lg[jj] - lg[0]);   // alpha_0

        const char* base = (const char*)(Ncolb + (size_t)b * NSEG * PSTR) + jj * 48;
        c0 = *(const int4*)(base);
        c1 = *(const int4*)(base + 16);
        c2 = *(const int4*)(base + 32);
        for (int s = 0; s < 16; ++s) {
            if (s < 15) {
                const char* p = base + (size_t)(s + 1) * (PSTR * 2);
                n0 = *(const int4*)(p);
                n1 = *(const int4*)(p + 16);
                n2 = *(const int4*)(p + 32);
            }
            float nv; PMV(a, c0, c1, c2, nv); a = nv;
            const float m = __uint_as_float(
                __builtin_amdgcn_readfirstlane(__float_as_uint(a)));
            a *= __builtin_amdgcn_rcpf(m);
            Orenorm += __logf(m);
            c0 = n0; c1 = n1; c2 = n2;
        }
    } else {
        // csum over t in [256, L)
        for (int t = 256 + lane; t < L; t += 64) csum += lg[t * NK];
        a = __expf(end_t[jj]);                   // beta at t = L-1

        const char* base = (const char*)(Nrowb + (size_t)b * NSEG * PSTR) + jj * 48;
        {
            const char* p = base + (size_t)31 * (PSTR * 2);
            c0 = *(const int4*)(p);
            c1 = *(const int4*)(p + 16);
            c2 = *(const int4*)(p + 32);
        }
        for (int s = 31; s >= 16; --s) {
            if (s > 16) {
                const char* p = base + (size_t)(s - 1) * (PSTR * 2);
                n0 = *(const int4*)(p);
                n1 = *(const int4*)(p + 16);
                n2 = *(const int4*)(p + 32);
            }
            float nv; PMV(a, c0, c1, c2, nv); a = nv;
            const float m = __uint_as_float(
                __builtin_amdgcn_readfirstlane(__float_as_uint(a)));
            a *= __builtin_amdgcn_rcpf(m);
            Orenorm += __logf(m);
            c0 = n0; c1 = n1; c2 = n2;
        }
    }
#undef RL
#undef PMV

    #pragma unroll
    for (int off = 32; off > 0; off >>= 1) csum += __shfl_xor(csum, off, 64);

    if (wid == 1) {
        if (lane < NK) comb[lane] = a;           // beta_m
        if (lane == 0) comb[21] = csum + Orenorm + rls;
    }
    __syncthreads();

    if (wid == 0) {
        float val = (lane < NK) ? a * comb[lane] : 0.f;
        #pragma unroll
        for (int off = 32; off > 0; off >>= 1) val += __shfl_xor(val, off, 64);
        if (lane == 0) {
            const float OF  = csum + Orenorm + rls;
            const float num = comb[22] + comb[23];
            atomicAdd(out + BSZ * SEQ * NK, OF + comb[21] + __logf(val) - num);
        }
    }
}

extern "C" void kernel_launch(void* const* d_in, const int* in_sizes, int n_in,
                              void* d_out, int out_size, void* d_ws, size_t ws_size,
                              hipStream_t stream)
{
    const float* hidden  = (const float*)d_in[0];
    const float* W       = (const float*)d_in[1];
    const float* bias    = (const float*)d_in[2];
    const float* start_t = (const float*)d_in[3];
    const float* trans   = (const float*)d_in[4];
    const float* end_t   = (const float*)d_in[5];
    const int*   labels  = (const int*)d_in[6];
    const int*   mask    = (const int*)d_in[7];
    float* out = (float*)d_out;

    char* ws = (char*)d_ws;
    unsigned short* WT    = (unsigned short*)ws;               // 48 KB
    int*            Lbuf  = (int*)(ws + 65536);                // 64 i
    float*          rlog  = (float*)(ws + 69632);              // 2048 f
    unsigned short* Nrowb = (unsigned short*)(ws + 131072);    // 2048*512 bf16 = 2 MB
    unsigned short* Ncolb = (unsigned short*)(ws + 131072 + 2 * 1024 * 1024);

    wconv_len_kernel<<<97, 256, 0, stream>>>(W, mask, WT, Lbuf, out);
    gemm_bias_kernel<<<(BSZ * SEQ) / 64, 256, 0, stream>>>(hidden, WT, bias, out);
    prepass_kernel<<<BSZ * NSEG, 64, 0, stream>>>(out, trans, Lbuf, Nrowb, Ncolb, rlog);
    scan_kernel<<<BSZ, 128, 0, stream>>>(out, start_t, trans, end_t, labels, Lbuf,
                                         Nrowb, Ncolb, rlog, out);
}

// Round 13
// 204.354 us; speedup vs baseline: 1.1997x; 1.0014x over previous
//
#include <hip/hip_runtime.h>

#define BSZ 64
#define SEQ 512
#define HID 768
#define NK  21
#define NSEG 32        // segments per batch
#define SEGLEN 16      // steps per segment (NSEG*SEGLEN == SEQ)
#define PSTR 512       // padded matrix stride in shorts (rows padded to 24; 1 KB/matrix)

typedef short bf16x8 __attribute__((ext_vector_type(8)));
typedef float f32x4  __attribute__((ext_vector_type(4)));

__device__ __forceinline__ unsigned f2bf1(float x) {   // RNE fp32->bf16
    unsigned u = __float_as_uint(x);
    return (u + 0x7fffu + ((u >> 16) & 1u)) >> 16;
}
__device__ __forceinline__ unsigned f2bf_pk(float lo, float hi) {
    return f2bf1(lo) | (f2bf1(hi) << 16);
}

// unpack bf16 pair packed in a dword (memory order: low short = even index)
#define U16L(d) __uint_as_float(((unsigned)(d)) << 16)
#define U16H(d) __uint_as_float(((unsigned)(d)) & 0xffff0000u)

// ------- W pre-convert (blocks 0..95) + per-batch lengths (block 96) --------
// Block 96 also zero-inits the nll output slot (scan atomicAdds into it).
__global__ __launch_bounds__(256) void wconv_len_kernel(
    const float* __restrict__ W, const int* __restrict__ mask,
    unsigned short* __restrict__ WT, int* __restrict__ Lbuf,
    float* __restrict__ out)
{
    if (blockIdx.x < 96) {
        const int idx = blockIdx.x * 256 + threadIdx.x;    // 0 .. 24575
        const int n = idx / HID;
        const int k = idx - n * HID;
        unsigned short v = 0;
        if (n < NK) v = (unsigned short)f2bf1(W[(size_t)k * NK + n]);
        WT[idx] = v;
    } else {
        const int tid = threadIdx.x;
        if (tid == 255) out[BSZ * SEQ * NK] = 0.f;         // nll accumulator
        const int b = tid >> 2, q = tid & 3;               // 4 threads per batch
        const int* msk = mask + b * SEQ + q * 128;
        int cnt = 0;
        for (int r = 0; r < 128; ++r) cnt += (msk[r] != 0);
        cnt += __shfl_xor(cnt, 1, 64);
        cnt += __shfl_xor(cnt, 2, 64);
        if (q == 0 && b < BSZ) Lbuf[b] = cnt;
    }
}

// ---------------- GEMM + bias (bf16 MFMA) — UNCHANGED from R12 ---------------
__global__ __launch_bounds__(256) void gemm_bias_kernel(
    const float* __restrict__ hidden, const unsigned short* __restrict__ WT,
    const float* __restrict__ bias, float* __restrict__ out)
{
    const int tid  = threadIdx.x;
    const int lane = tid & 63;
    const int wv   = tid >> 6;
    const int n    = lane & 15;
    const int quad = lane >> 4;

    const int arow = blockIdx.x * 64 + wv * 16 + n;
    const float* ap = hidden + (size_t)arow * HID + quad * 8;
    const bf16x8* bp0 = (const bf16x8*)(WT + (size_t)n * HID + quad * 8);
    const bf16x8* bp1 = (const bf16x8*)(WT + (size_t)(16 + n) * HID + quad * 8);

    f32x4 acc0 = {0.f, 0.f, 0.f, 0.f};
    f32x4 acc1 = {0.f, 0.f, 0.f, 0.f};

    // prefetch: A chunks 0,1; B chunk 0
    float4 a0 = *(const float4*)(ap + 0);
    float4 a1 = *(const float4*)(ap + 4);
    float4 p0 = *(const float4*)(ap + 32);
    float4 p1 = *(const float4*)(ap + 36);
    bf16x8 B0 = bp0[0];
    bf16x8 B1 = bp1[0];

    #pragma unroll
    for (int c = 0; c < HID / 32; ++c) {               // 24 K-chunks
        float4 q0, q1; bf16x8 Bn0, Bn1;
        if (c + 2 < HID / 32) {                        // A depth-2
            q0 = *(const float4*)(ap + (c + 2) * 32);
            q1 = *(const float4*)(ap + (c + 2) * 32 + 4);
        }
        if (c + 1 < HID / 32) {                        // B depth-1
            Bn0 = bp0[(c + 1) * 4];
            Bn1 = bp1[(c + 1) * 4];
        }
        union { bf16x8 v; unsigned u[4]; } af;
        af.u[0] = f2bf_pk(a0.x, a0.y);
        af.u[1] = f2bf_pk(a0.z, a0.w);
        af.u[2] = f2bf_pk(a1.x, a1.y);
        af.u[3] = f2bf_pk(a1.z, a1.w);

        acc0 = __builtin_amdgcn_mfma_f32_16x16x32_bf16(af.v, B0, acc0, 0, 0, 0);
        acc1 = __builtin_amdgcn_mfma_f32_16x16x32_bf16(af.v, B1, acc1, 0, 0, 0);

        a0 = p0; a1 = p1; p0 = q0; p1 = q1;
        B0 = Bn0; B1 = Bn1;
    }

    const float b0v = bias[n];
    const float b1v = (n < NK - 16) ? bias[16 + n] : 0.f;
    const int rbase = blockIdx.x * 64 + wv * 16 + quad * 4;
    #pragma unroll
    for (int r = 0; r < 4; ++r) {
        float* op = out + (size_t)(rbase + r) * NK;
        op[n] = acc0[r] + b0v;
        if (n < NK - 16) op[16 + n] = acc1[r] + b1v;
    }
}

// ---------------- CRF pre-pass: per-segment matrix products (bf16 out) -------
// One wave per (b, s). E held packed bf16 (no scratch spill). rlog[bs] now
// carries BOTH the renorm logs AND the segment's sum of offsets C[t]
// (t in [16s+1, 16s+16] intersect [0,L)) -- scan's csum loops are deleted.
#define EHI(u) __uint_as_float((u) & 0xffff0000u)
#define ELO(u) __uint_as_float((u) << 16)
__global__ __launch_bounds__(64, 2) void prepass_kernel(
    const float* __restrict__ logits, const float* __restrict__ trans,
    const int* __restrict__ Lbuf,
    unsigned short* __restrict__ Nrowb, unsigned short* __restrict__ Ncolb,
    float* __restrict__ rlog)
{
    const int bs   = blockIdx.x;                 // b*NSEG + s
    const int b    = bs >> 5;
    const int s    = bs & 31;
    const int lane = threadIdx.x;
    int g = lane / 21; if (g > 2) g = 2;         // lane 63 duplicates (20,2)
    int i = lane - g * 21; if (i > 20) i = 20;
    const int j0 = 7 * g;

    const int L = Lbuf[b];

    // Epk[jl][p]: bf16(E[2p][j0+jl]) high16, bf16(E[2p+1][j0+jl]) low16
    unsigned Epk[7][11];
    #pragma unroll
    for (int jl = 0; jl < 7; ++jl)
        #pragma unroll
        for (int p = 0; p < 11; ++p) {
            const float ehi = __expf(trans[(2 * p) * NK + j0 + jl]);
            const float elo = (2 * p + 1 < 21)
                            ? __expf(trans[(2 * p + 1) * NK + j0 + jl]) : 0.f;
            Epk[jl][p] = (f2bf1(ehi) << 16) | f2bf1(elo);
        }

    const float* lg = logits + (size_t)b * SEQ * NK;

    float P[7];
    float rl = 0.f;                              // segment C-sum + renorm logs
    const int t0 = s * SEGLEN + 1;

    if (t0 < L) {                                // P := M_{t0}
        const float C = lg[t0 * NK];
        rl = C;
        #pragma unroll
        for (int jl = 0; jl < 7; ++jl)
            P[jl] = __expf(trans[i * NK + j0 + jl])
                  * __expf(lg[t0 * NK + j0 + jl] - C);
    } else {                                     // identity
        #pragma unroll
        for (int jl = 0; jl < 7; ++jl) P[jl] = (i == j0 + jl) ? 1.f : 0.f;
    }

#define BPF(v, idx) __uint_as_float(__builtin_amdgcn_ds_bpermute((idx) * 4, __float_as_uint(v)))

    #pragma unroll
    for (int u = 1; u < SEGLEN; ++u) {
        const int t = t0 + u;
        if (t < L) {                             // wave-uniform branch
            float row[22];                       // row i of current P (+ pad)
            #pragma unroll
            for (int k = 0; k < 21; ++k)
                row[k] = BPF(P[k % 7], (k / 7) * 21 + i);
            row[21] = 0.f;

            const float C = lg[t * NK];
            rl += C;
            float X[7];
            #pragma unroll
            for (int jl = 0; jl < 7; ++jl)
                X[jl] = __expf(lg[t * NK + j0 + jl] - C);

            #pragma unroll
            for (int jl = 0; jl < 7; ++jl) {
                float s0 = 0.f, s1 = 0.f;
                #pragma unroll
                for (int p = 0; p < 11; ++p) {
                    const unsigned e = Epk[jl][p];
                    s0 = fmaf(row[2 * p    ], EHI(e), s0);
                    s1 = fmaf(row[2 * p + 1], ELO(e), s1);
                }
                P[jl] = (s0 + s1) * X[jl];
            }
            const float m = BPF(P[0], 0);        // entry [0][0]
            const float r = __builtin_amdgcn_rcpf(m);
            #pragma unroll
            for (int jl = 0; jl < 7; ++jl) P[jl] *= r;
            rl += __logf(m);
        }
    }
#undef BPF

    if (lane < 63) {                             // lane 63 is a duplicate
        unsigned short* nr = Nrowb + (size_t)bs * PSTR + i * 24 + j0;
        #pragma unroll
        for (int jl = 0; jl < 7; ++jl) nr[jl] = (unsigned short)f2bf1(P[jl]);
        unsigned short* nc = Ncolb + (size_t)bs * PSTR + i;
        #pragma unroll
        for (int jl = 0; jl < 7; ++jl)
            nc[(j0 + jl) * 24] = (unsigned short)f2bf1(P[jl]);
    }
    if (lane == 0) rlog[bs] = rl;
}

// ---------------- CRF scan: 16 matrix-vector steps; nll via atomicAdd --------
__global__ __launch_bounds__(128) void scan_kernel(
    const float* __restrict__ logits,
    const float* __restrict__ start_t,
    const float* __restrict__ trans,
    const float* __restrict__ end_t,
    const int* __restrict__ labels,
    const int* __restrict__ Lbuf,
    const unsigned short* __restrict__ Nrowb,
    const unsigned short* __restrict__ Ncolb,
    const float* __restrict__ rlog,
    float* __restrict__ out)
{
    __shared__ float comb[26];                   // [0..20] beta_m, [21] OB, [22/23] num

    const int b    = blockIdx.x;
    const int tid  = threadIdx.x;
    const int lane = tid & 63;
    const int wid  = tid >> 6;                   // 0 = forward, 1 = backward

    const float* lg = logits + (size_t)b * SEQ * NK;
    const int* lab = labels + b * SEQ;
    const int L = Lbuf[b];

    {   // numerator partials over 128 threads
        float numacc = 0.f;
        for (int t = tid; t < L; t += 128) {
            if (t == 0) numacc += start_t[lab[0]] + lg[lab[0]];
            else        numacc += lg[t * NK + lab[t]] + trans[lab[t - 1] * NK + lab[t]];
        }
        if (tid == 0) numacc += end_t[lab[L - 1]];
        #pragma unroll
        for (int off = 32; off > 0; off >>= 1) numacc += __shfl_xor(numacc, off, 64);
        if (lane == 0) comb[22 + wid] = numacc;
    }

    // rlog partial (C-sums + renorm logs): fwd sums s=0..15, bwd s=16..31
    float rls = (lane < 16) ? rlog[b * NSEG + wid * 16 + lane] : 0.f;
    #pragma unroll
    for (int off = 32; off > 0; off >>= 1) rls += __shfl_xor(rls, off, 64);

    const int jj = (lane < NK) ? lane : NK - 1;

#define RL(v, k) __uint_as_float(__builtin_amdgcn_readlane(__float_as_uint(v), k))
// 21-term matvec from packed bf16 row held in 3 int4:
#define PMV(vv, c0, c1, c2, outv) do {                                        \
    float s0 = RL(vv, 0) * U16L(c0.x);                                        \
    float s1 = RL(vv, 1) * U16H(c0.x);                                        \
    float s2 = RL(vv, 2) * U16L(c0.y);                                        \
    s0 = fmaf(RL(vv,  3), U16H(c0.y), s0); s1 = fmaf(RL(vv,  4), U16L(c0.z), s1); \
    s2 = fmaf(RL(vv,  5), U16H(c0.z), s2); s0 = fmaf(RL(vv,  6), U16L(c0.w), s0); \
    s1 = fmaf(RL(vv,  7), U16H(c0.w), s1); s2 = fmaf(RL(vv,  8), U16L(c1.x), s2); \
    s0 = fmaf(RL(vv,  9), U16H(c1.x), s0); s1 = fmaf(RL(vv, 10), U16L(c1.y), s1); \
    s2 = fmaf(RL(vv, 11), U16H(c1.y), s2); s0 = fmaf(RL(vv, 12), U16L(c1.z), s0); \
    s1 = fmaf(RL(vv, 13), U16H(c1.z), s1); s2 = fmaf(RL(vv, 14), U16L(c1.w), s2); \
    s0 = fmaf(RL(vv, 15), U16H(c1.w), s0); s1 = fmaf(RL(vv, 16), U16L(c2.x), s1); \
    s2 = fmaf(RL(vv, 17), U16H(c2.x), s2); s0 = fmaf(RL(vv, 18), U16L(c2.y), s0); \
    s1 = fmaf(RL(vv, 19), U16H(c2.y), s1); s2 = fmaf(RL(vv, 20), U16L(c2.z), s2); \
    outv = (s0 + s1) + s2;                                                    \
} while (0)

    float a, Orenorm = 0.f;
    int4 c0, c1, c2, n0, n1, n2;

    if (wid == 0) {
        a = __expf(start_t[jj]) * __expf(lg[jj] - lg[0]);   // alpha_0 (offset C[0])

        const char* base = (const char*)(Ncolb + (size_t)b * NSEG * PSTR) + jj * 48;
        c0 = *(const int4*)(base);
        c1 = *(const int4*)(base + 16);
        c2 = *(const int4*)(base + 32);
        for (int s = 0; s < 16; ++s) {
            if (s < 15) {
                const char* p = base + (size_t)(s + 1) * (PSTR * 2);
                n0 = *(const int4*)(p);
                n1 = *(const int4*)(p + 16);
                n2 = *(const int4*)(p + 32);
            }
            float nv; PMV(a, c0, c1, c2, nv); a = nv;
            const float m = __uint_as_float(
                __builtin_amdgcn_readfirstlane(__float_as_uint(a)));
            a *= __builtin_amdgcn_rcpf(m);
            Orenorm += __logf(m);
            c0 = n0; c1 = n1; c2 = n2;
        }
    } else {
        a = __expf(end_t[jj]);                   // beta at t = L-1

        const char* base = (const char*)(Nrowb + (size_t)b * NSEG * PSTR) + jj * 48;
        {
            const char* p = base + (size_t)31 * (PSTR * 2);
            c0 = *(const int4*)(p);
            c1 = *(const int4*)(p + 16);
            c2 = *(const int4*)(p + 32);
        }
        for (int s = 31; s >= 16; --s) {
            if (s > 16) {
                const char* p = base + (size_t)(s - 1) * (PSTR * 2);
                n0 = *(const int4*)(p);
                n1 = *(const int4*)(p + 16);
                n2 = *(const int4*)(p + 32);
            }
            float nv; PMV(a, c0, c1, c2, nv); a = nv;
            const float m = __uint_as_float(
                __builtin_amdgcn_readfirstlane(__float_as_uint(a)));
            a *= __builtin_amdgcn_rcpf(m);
            Orenorm += __logf(m);
            c0 = n0; c1 = n1; c2 = n2;
        }
    }
#undef RL
#undef PMV

    if (wid == 1) {
        if (lane < NK) comb[lane] = a;           // beta_m
        if (lane == 0) comb[21] = Orenorm + rls; // OB (C-sums live in rls)
    }
    __syncthreads();

    if (wid == 0) {
        float val = (lane < NK) ? a * comb[lane] : 0.f;
        #pragma unroll
        for (int off = 32; off > 0; off >>= 1) val += __shfl_xor(val, off, 64);
        if (lane == 0) {
            const float OF  = Orenorm + rls + lg[0];        // + C[0]
            const float num = comb[22] + comb[23];
            atomicAdd(out + BSZ * SEQ * NK, OF + comb[21] + __logf(val) - num);
        }
    }
}

extern "C" void kernel_launch(void* const* d_in, const int* in_sizes, int n_in,
                              void* d_out, int out_size, void* d_ws, size_t ws_size,
                              hipStream_t stream)
{
    const float* hidden  = (const float*)d_in[0];
    const float* W       = (const float*)d_in[1];
    const float* bias    = (const float*)d_in[2];
    const float* start_t = (const float*)d_in[3];
    const float* trans   = (const float*)d_in[4];
    const float* end_t   = (const float*)d_in[5];
    const int*   labels  = (const int*)d_in[6];
    const int*   mask    = (const int*)d_in[7];
    float* out = (float*)d_out;

    char* ws = (char*)d_ws;
    unsigned short* WT    = (unsigned short*)ws;               // 48 KB
    int*            Lbuf  = (int*)(ws + 65536);                // 64 i
    float*          rlog  = (float*)(ws + 69632);              // 2048 f
    unsigned short* Nrowb = (unsigned short*)(ws + 131072);    // 2048*512 bf16 = 2 MB
    unsigned short* Ncolb = (unsigned short*)(ws + 131072 + 2 * 1024 * 1024);

    wconv_len_kernel<<<97, 256, 0, stream>>>(W, mask, WT, Lbuf, out);
    gemm_bias_kernel<<<(BSZ * SEQ) / 64, 256, 0, stream>>>(hidden, WT, bias, out);
    prepass_kernel<<<BSZ * NSEG, 64, 0, stream>>>(out, trans, Lbuf, Nrowb, Ncolb, rlog);
    scan_kernel<<<BSZ, 128, 0, stream>>>(out, start_t, trans, end_t, labels, Lbuf,
                                         Nrowb, Ncolb, rlog, out);
}